// Round 1
// baseline (161.448 us; speedup 1.0000x reference)
//
#include <hip/hip_runtime.h>

#define V_DIMC 2048
#define Q_DIMC 1024
#define BATCH  64
#define KC     36
#define MROWS  (BATCH * KC)          // 2304
#define W1LD   (2 * V_DIMC + Q_DIMC) // 5120

typedef __bf16 bf16_t;
typedef __attribute__((ext_vector_type(8))) __bf16 bf16x8;
typedef __attribute__((ext_vector_type(4))) __bf16 bf16x4;
typedef __attribute__((ext_vector_type(4))) float f32x4;

__device__ __forceinline__ void gload16(const bf16_t* g, bf16_t* l) {
    __builtin_amdgcn_global_load_lds(
        (const __attribute__((address_space(1))) unsigned int*)(g),
        (__attribute__((address_space(3))) unsigned int*)(l), 16, 0, 0);
}

#define MFMAI(a, b, c) __builtin_amdgcn_mfma_f32_16x16x32_bf16(a, b, c, 0, 0, 0)
#define BARX() __builtin_amdgcn_s_barrier()
#define LGKM0() asm volatile("s_waitcnt lgkmcnt(0)" ::: "memory")
#define VMC(n)  asm volatile("s_waitcnt vmcnt(" #n ")" ::: "memory")

// ---------------- fused fp32 -> bf16 conversion of all operands ----------------
__global__ __launch_bounds__(256) void conv_all(const float* __restrict__ v,
                                                const float* __restrict__ q,
                                                const float* __restrict__ W1,
                                                const float* __restrict__ W2,
                                                const float* __restrict__ W3,
                                                bf16_t* __restrict__ Wab,
                                                bf16_t* __restrict__ W2b,
                                                bf16_t* __restrict__ vb,
                                                bf16_t* __restrict__ W3b,
                                                bf16_t* __restrict__ Wcb,
                                                bf16_t* __restrict__ qb) {
    const int t = blockIdx.x * 256 + threadIdx.x;
    const float* src;
    bf16_t* dst;
    if (t < 2097152) {
        size_t idx = (size_t)t * 4;
        int row = (int)(idx >> 11), col = (int)(idx & 2047);
        src = (row < 2048) ? W1 + (size_t)row * W1LD + col
                           : W1 + (size_t)(row - 2048) * W1LD + V_DIMC + col;
        dst = Wab + idx;
    } else if (t < 3145728) {
        size_t idx = (size_t)(t - 2097152) * 4;
        src = W2 + idx; dst = W2b + idx;
    } else if (t < 4325376) {
        size_t idx = (size_t)(t - 3145728) * 4;
        src = v + idx; dst = vb + idx;
    } else if (t < 4587520) {
        size_t idx = (size_t)(t - 4325376) * 4;
        src = W3 + idx; dst = W3b + idx;
    } else if (t < 5111808) {
        size_t idx = (size_t)(t - 4587520) * 4;
        int row = (int)(idx >> 10), col = (int)(idx & 1023);
        src = W1 + (size_t)row * W1LD + 2 * V_DIMC + col;
        dst = Wcb + idx;
    } else {
        size_t idx = (size_t)(t - 5111808) * 4;
        src = q + idx; dst = qb + idx;
    }
    float4 f = *reinterpret_cast<const float4*>(src);
    bf16x4 o;
    o[0] = (bf16_t)f.x; o[1] = (bf16_t)f.y; o[2] = (bf16_t)f.z; o[3] = (bf16_t)f.w;
    *reinterpret_cast<bf16x4*>(dst) = o;
}

// ---------------- M=64 MFMA GEMM (q-path) ----------------
template <int NDIM, int KDIM, int MODE>
__global__ __launch_bounds__(256) void mfma_gemm64(const bf16_t* __restrict__ A,
                                                   const bf16_t* __restrict__ B,
                                                   void* __restrict__ out,
                                                   const float* __restrict__ bias) {
    __shared__ bf16_t As[64][32];
    __shared__ bf16_t Bs[128][32];
    const int n0 = blockIdx.x * 128;
    const int tid = threadIdx.x;
    const int w = tid >> 6, l = tid & 63;
    const int srow = tid >> 2;
    const int scol = (tid & 3) * 8;
    const bf16_t* Ag  = A + (size_t)srow * KDIM + scol;
    const bf16_t* Bg0 = B + (size_t)(n0 + srow) * KDIM + scol;
    const bf16_t* Bg1 = B + (size_t)(n0 + 64 + srow) * KDIM + scol;
    bf16_t* ldsA  = &As[w * 16][0];
    bf16_t* ldsB0 = &Bs[w * 16][0];
    bf16_t* ldsB1 = &Bs[64 + w * 16][0];
    const int fr = l & 15, fko = (l >> 4) * 8;

    f32x4 acc[4][2] = {};
    for (int k0 = 0; k0 < KDIM; k0 += 32) {
        gload16(Ag + k0, ldsA);
        gload16(Bg0 + k0, ldsB0);
        gload16(Bg1 + k0, ldsB1);
        __syncthreads();
        bf16x8 af[4], bfr[2];
#pragma unroll
        for (int m = 0; m < 4; ++m)
            af[m] = *reinterpret_cast<const bf16x8*>(&As[m * 16 + fr][fko]);
#pragma unroll
        for (int n = 0; n < 2; ++n)
            bfr[n] = *reinterpret_cast<const bf16x8*>(&Bs[w * 32 + n * 16 + fr][fko]);
#pragma unroll
        for (int m = 0; m < 4; ++m)
#pragma unroll
            for (int n = 0; n < 2; ++n)
                acc[m][n] = MFMAI(af[m], bfr[n], acc[m][n]);
        __syncthreads();
    }
    const int col = l & 15, rb = (l >> 4) * 4;
#pragma unroll
    for (int m = 0; m < 4; ++m)
#pragma unroll
        for (int n = 0; n < 2; ++n) {
            const int gn = n0 + w * 32 + n * 16 + col;
            const float bs = bias[gn];
#pragma unroll
            for (int r = 0; r < 4; ++r) {
                const int gm = m * 16 + rb + r;
                const float val = acc[m][n][r];
                if (MODE == 0)
                    ((bf16_t*)out)[(size_t)gm * NDIM + gn] = (bf16_t)fmaxf(val + bs, 0.f);
                else
                    ((float*)out)[(size_t)gm * NDIM + gn] = val + bs;
            }
        }
}

// ---------------- 256x256 8-phase MFMA GEMM: C[M][N] = A[M][K] * B[N][K]^T ----
// 512 threads = 8 waves (2M x 4N), wave tile 128x64, BK=64, double-buffered
// 128 KiB LDS. LDS XOR-swizzle (byte ^= (row&7)<<4) applied via inverse-
// swizzled global source (global_load_lds dest stays linear) + swizzled
// ds_read. Raw s_barrier + counted vmcnt — NO __syncthreads in the K-loop.
// Phase schedule per K-tile T (4 phases, 2 barriers each):
//   ph1: read A-mh0(8)+B-nh0(4); stage (T+1).A0  -> other buf
//   ph2: read B-nh1(4);          stage (T+1).A1  -> other buf
//   ph3: read A-mh1(8);          stage (T+2).B0  -> this buf (B reads done ph2)
//   ph4: (pure MFMA);            stage (T+2).B1; vmcnt(4)  [vmcnt(0) at tail]
// Overwrite safety: a slot is staged only after the barrier that follows the
// lgkmcnt(0)-drained last read of its previous content (verified per-slot).
// MODE 0: out split at n=2048 -> out0/out1 (bf16, no bias). K=2048, NT=32.
// MODE 2: split-K partial (blockIdx.z selects K-half), bf16 partial to
//         out0 (z=0) / out1 (z=1). NT=16.
template <int MODE>
__global__ __launch_bounds__(512) void gemm8p(const bf16_t* __restrict__ A,
                                              const bf16_t* __restrict__ Bm,
                                              bf16_t* __restrict__ out0,
                                              bf16_t* __restrict__ out1) {
    constexpr int K = 2048;
    constexpr int NT = (MODE == 2) ? 16 : 32;
    __shared__ bf16_t lds[8][128 * 64];   // [buf*4 + mat*2 + half][row*64+col]
    const int tid = threadIdx.x;
    const int w = tid >> 6, l = tid & 63;
    const int wm = w >> 2, wn = w & 3;
    const int m0 = blockIdx.y * 256;
    const int n0 = blockIdx.x * 256;
    const int kb = (MODE == 2) ? (int)blockIdx.z * 1024 : 0;

    // ---- staging: thread covers (row = tid>>3 [+64 step1], col-unit tid&7).
    // physical slot cu holds logical lcu = cu ^ (row&7)  (inverse swizzle on
    // the GLOBAL source; LDS write is linear: wave base + lane*16).
    const int srow = tid >> 3;
    const int slcu = ((tid & 7) ^ (srow & 7)) << 3;    // element offset in BK
    const size_t sK = (size_t)K;
    const bf16_t* gA = A  + (size_t)(m0 + srow) * sK + kb + slcu;
    const bf16_t* gB = Bm + (size_t)(n0 + srow) * sK + kb + slcu;
    const int stW = (w * 64) * 8;                      // step-0 elem offset

#define STG(mat, h, T) do {                                                   \
        const bf16_t* g_ = (mat ? gB : gA) + (size_t)((h) * 128) * sK         \
                           + (size_t)(T) * 64;                                \
        bf16_t* d_ = &lds[(((T) & 1) << 2) | ((mat) << 1) | (h)][stW];        \
        gload16(g_, d_);                                                      \
        gload16(g_ + (size_t)64 * sK, d_ + 512 * 8);                          \
    } while (0)

    // ---- fragment reads: row = frag*16+fr, logical col-unit = ks*4+lq,
    // physical byte = row*128 + ((ks*4+lq)^(fr&7))*16   (row&7 == fr&7).
    const int fr = l & 15, lq = l >> 4;
    const int sw0 = (lq ^ (fr & 7)) << 4;
    const int sw1 = ((4 | lq) ^ (fr & 7)) << 4;

    f32x4 acc[8][4] = {};

    // prologue: all of tile0, B-halves of tile1 (A-halves of t1 come in ph1/2)
    STG(0, 0, 0); STG(0, 1, 0); STG(1, 0, 0); STG(1, 1, 0);
    STG(1, 0, 1); STG(1, 1, 1);
    VMC(4);              // tile0 landed; tile1.B0/B1 (4 loads) still in flight
    BARX();

    for (int T = 0; T < NT; ++T) {
        const char* pa = (const char*)&lds[((T & 1) << 2) | wm][0];
        const char* pb = (const char*)&lds[((T & 1) << 2) | 2 | (wn >> 1)][0];
        const int br = (wn & 1) * 64;
        bf16x8 aF[4][2], bF[4][2];

        // ---------------- phase 1: quadrant (mh0, nh0) ----------------
#pragma unroll
        for (int mi = 0; mi < 4; ++mi) {
            const int ro = (mi * 16 + fr) * 128;
            aF[mi][0] = *(const bf16x8*)(pa + ro + sw0);
            aF[mi][1] = *(const bf16x8*)(pa + ro + sw1);
        }
#pragma unroll
        for (int ni = 0; ni < 2; ++ni) {
            const int ro = (br + ni * 16 + fr) * 128;
            bF[ni][0] = *(const bf16x8*)(pb + ro + sw0);
            bF[ni][1] = *(const bf16x8*)(pb + ro + sw1);
        }
        if (T + 1 < NT) STG(0, 0, T + 1);
        BARX(); LGKM0();
        __builtin_amdgcn_s_setprio(1);
#pragma unroll
        for (int mi = 0; mi < 4; ++mi)
#pragma unroll
            for (int ni = 0; ni < 2; ++ni) {
                acc[mi][ni] = MFMAI(aF[mi][0], bF[ni][0], acc[mi][ni]);
                acc[mi][ni] = MFMAI(aF[mi][1], bF[ni][1], acc[mi][ni]);
            }
        __builtin_amdgcn_s_setprio(0);
        BARX();

        // ---------------- phase 2: quadrant (mh0, nh1) ----------------
#pragma unroll
        for (int ni = 2; ni < 4; ++ni) {
            const int ro = (br + ni * 16 + fr) * 128;
            bF[ni][0] = *(const bf16x8*)(pb + ro + sw0);
            bF[ni][1] = *(const bf16x8*)(pb + ro + sw1);
        }
        if (T + 1 < NT) STG(0, 1, T + 1);
        BARX(); LGKM0();
        __builtin_amdgcn_s_setprio(1);
#pragma unroll
        for (int mi = 0; mi < 4; ++mi)
#pragma unroll
            for (int ni = 2; ni < 4; ++ni) {
                acc[mi][ni] = MFMAI(aF[mi][0], bF[ni][0], acc[mi][ni]);
                acc[mi][ni] = MFMAI(aF[mi][1], bF[ni][1], acc[mi][ni]);
            }
        __builtin_amdgcn_s_setprio(0);
        BARX();

        // ---------------- phase 3: quadrant (mh1, nh0) ----------------
#pragma unroll
        for (int mi = 0; mi < 4; ++mi) {
            const int ro = (64 + mi * 16 + fr) * 128;
            aF[mi][0] = *(const bf16x8*)(pa + ro + sw0);   // reuse aF regs
            aF[mi][1] = *(const bf16x8*)(pa + ro + sw1);
        }
        if (T + 2 < NT) STG(1, 0, T + 2);   // B reads finished by ph2 BAR
        BARX(); LGKM0();
        __builtin_amdgcn_s_setprio(1);
#pragma unroll
        for (int mi = 0; mi < 4; ++mi)
#pragma unroll
            for (int ni = 0; ni < 2; ++ni) {
                acc[4 + mi][ni] = MFMAI(aF[mi][0], bF[ni][0], acc[4 + mi][ni]);
                acc[4 + mi][ni] = MFMAI(aF[mi][1], bF[ni][1], acc[4 + mi][ni]);
            }
        __builtin_amdgcn_s_setprio(0);
        BARX();

        // ---------------- phase 4: quadrant (mh1, nh1) ----------------
        if (T + 2 < NT) STG(1, 1, T + 2);
        BARX(); LGKM0();
        __builtin_amdgcn_s_setprio(1);
#pragma unroll
        for (int mi = 0; mi < 4; ++mi)
#pragma unroll
            for (int ni = 2; ni < 4; ++ni) {
                acc[4 + mi][ni] = MFMAI(aF[mi][0], bF[ni][0], acc[4 + mi][ni]);
                acc[4 + mi][ni] = MFMAI(aF[mi][1], bF[ni][1], acc[4 + mi][ni]);
            }
        __builtin_amdgcn_s_setprio(0);
        // tile T+1 fully staged once the 4 loads younger than (T+1).A1
        // ((T+2).B0/B1) are the only ones outstanding. At the tail those
        // stages were skipped, so drain fully.
        if (T < NT - 2) { VMC(4); } else { VMC(0); }
        BARX();
    }
#undef STG

    // ---------------- epilogue ----------------
    bf16_t* o;
    int gn0;
    if (MODE == 0) {
        if (n0 < V_DIMC) { o = out0; gn0 = n0; }
        else             { o = out1; gn0 = n0 - V_DIMC; }
    } else {
        o = blockIdx.z ? out1 : out0; gn0 = n0;
    }
    const int rb = lq * 4;
#pragma unroll
    for (int mi = 0; mi < 8; ++mi)
#pragma unroll
        for (int ni = 0; ni < 4; ++ni) {
            const size_t gm = (size_t)(m0 + wm * 128 + mi * 16 + rb);
            const int gn = gn0 + wn * 64 + ni * 16 + fr;
#pragma unroll
            for (int r = 0; r < 4; ++r)
                o[(gm + r) * V_DIMC + gn] = (bf16_t)acc[mi][ni][r];
        }
}

// ---------------- reduce: out = relu(p0 + p1 + b2) ----------------
__global__ __launch_bounds__(256) void reduce_out(const bf16_t* __restrict__ p0,
                                                  const bf16_t* __restrict__ p1,
                                                  const float* __restrict__ b2,
                                                  float* __restrict__ out) {
    const size_t t = (size_t)blockIdx.x * 256 + threadIdx.x;
    const size_t idx = t * 8;
    bf16x8 a = *reinterpret_cast<const bf16x8*>(p0 + idx);
    bf16x8 b = *reinterpret_cast<const bf16x8*>(p1 + idx);
    const int col = (int)(idx & (V_DIMC - 1));
    float4 r0, r1;
    float* rr[2] = {&r0.x, &r1.x};
#pragma unroll
    for (int h = 0; h < 2; ++h)
#pragma unroll
        for (int j = 0; j < 4; ++j)
            rr[h][j] = fmaxf((float)a[h * 4 + j] + (float)b[h * 4 + j] + b2[col + h * 4 + j], 0.f);
    *reinterpret_cast<float4*>(out + idx) = r0;
    *reinterpret_cast<float4*>(out + idx + 4) = r1;
}

// ---------------- pairwise: X[b,k,v] = sum_j relu(A[b,k,v] + Bp[b,j,v] + c[b,v]) ----------------
__global__ __launch_bounds__(256) void pair_kernel(const bf16_t* __restrict__ A,
                                                   const bf16_t* __restrict__ Bp,
                                                   const float* __restrict__ cbuf,
                                                   bf16_t* __restrict__ X) {
    const int v = blockIdx.x * 256 + threadIdx.x;
    const int b = blockIdx.y;
    const float cc = cbuf[b * V_DIMC + v];
    const bf16_t* Ab = A + (size_t)b * KC * V_DIMC + v;
    const bf16_t* Bb = Bp + (size_t)b * KC * V_DIMC + v;
    float av[KC], bv[KC];
#pragma unroll
    for (int k = 0; k < KC; ++k) {
        av[k] = (float)Ab[(size_t)k * V_DIMC] + cc;
        bv[k] = (float)Bb[(size_t)k * V_DIMC];
    }
    bf16_t* Xb = X + (size_t)b * KC * V_DIMC + v;
#pragma unroll
    for (int k = 0; k < KC; ++k) {
        float s = 0.f;
#pragma unroll
        for (int j = 0; j < KC; ++j) s += fmaxf(av[k] + bv[j], 0.f);
        Xb[(size_t)k * V_DIMC] = (bf16_t)s;
    }
}

extern "C" void kernel_launch(void* const* d_in, const int* in_sizes, int n_in,
                              void* d_out, int out_size, void* d_ws, size_t ws_size,
                              hipStream_t stream) {
    const float* v  = (const float*)d_in[0];
    const float* q  = (const float*)d_in[1];
    const float* W1 = (const float*)d_in[2];
    const float* b1 = (const float*)d_in[3];
    const float* W2 = (const float*)d_in[4];
    const float* b2 = (const float*)d_in[5];
    const float* W3 = (const float*)d_in[6];
    const float* b3 = (const float*)d_in[7];
    float* out = (float*)d_out;

    char* wsb = (char*)d_ws;
    bf16_t* Wab_b = (bf16_t*)wsb;                            // 16 MiB; later Xb
    bf16_t* W2b   = (bf16_t*)(wsb + 16777216ull);            // 8 MiB
    bf16_t* vb    = (bf16_t*)(wsb + 25165824ull);            // 9 MiB
    bf16_t* Abf   = (bf16_t*)(wsb + 34603008ull);            // 9 MiB; later partial0
    bf16_t* W3b   = (bf16_t*)(wsb + 34603008ull);            // alias (2 MiB)
    bf16_t* Wcb   = (bf16_t*)(wsb + 34603008ull + 2097152);  // alias (4 MiB)
    bf16_t* qb    = (bf16_t*)(wsb + 34603008ull + 6291456);  // alias (128 KiB)
    bf16_t* Bbf   = (bf16_t*)(wsb + 44040192ull);            // 9 MiB; later partial1
    bf16_t* qemb  = (bf16_t*)(wsb + 53477376ull);
    float*  cbuf  = (float*) (wsb + 53608448ull);
    bf16_t* Xb    = Wab_b;

    conv_all<<<dim3(20032), 256, 0, stream>>>(v, q, W1, W2, W3, Wab_b, W2b, vb, W3b, Wcb, qb);
    mfma_gemm64<Q_DIMC, Q_DIMC, 0><<<dim3(Q_DIMC / 128), 256, 0, stream>>>(qb, W3b, qemb, b3);
    mfma_gemm64<V_DIMC, Q_DIMC, 1><<<dim3(V_DIMC / 128), 256, 0, stream>>>(qemb, Wcb, cbuf, b1);

    // a / bpart: M=2304, N=4096 (Wa|Wb), K=2048 — 144 blocks of 256x256
    gemm8p<0><<<dim3(4096 / 256, MROWS / 256), 512, 0, stream>>>(vb, Wab_b, Abf, Bbf);
    pair_kernel<<<dim3(V_DIMC / 256, BATCH), 256, 0, stream>>>(Abf, Bbf, cbuf, Xb);
    // final GEMM, split-K over z: partials into Abf (z=0) / Bbf (z=1)
    gemm8p<2><<<dim3(V_DIMC / 256, MROWS / 256, 2), 512, 0, stream>>>(Xb, W2b, Abf, Bbf);
    reduce_out<<<dim3((MROWS * V_DIMC / 8) / 256), 256, 0, stream>>>(Abf, Bbf, b2, out);
}